// Round 12
// baseline (81.545 us; speedup 1.0000x reference)
//
#include <hip/hip_runtime.h>

// Two-kernel MFMA-tail, take 8b: Rot-folded W + permlane32_swap, LDS-free main.
// Round-11 failed on a TYPE error only (cvt_pkrtz returns __fp16x2, not
// _Float16x2); logic unchanged. Permlane algebra re-verified against
// v_permlane32_swap_b32 semantics (row1-of-A <-> row0-of-B):
//   newA = tile0 B-fragment, newB = tile1 B-fragment, both lane halves --
//   identical data to round-10's LDS reads (srow + h*16 / +32).
//  1) Layer-0 Rot gates are sample-independent -> folded into W at compose.
//  2) 8 permlane32_swap replace the LDS slab + fence entirely (LDS-free main).
// cvt_pkrtz is RTZ (2^-11 rel) vs prior RTN (2^-12): within the 0.0198
// threshold's 5x headroom. Fallbacks: absmax blowup -> revert to r10 LDS path
// (keep Rot-fold); WRITE_SIZE balloon -> spill -> (256,6).

using f16x8  = __attribute__((ext_vector_type(8))) _Float16;
using hf2    = __attribute__((ext_vector_type(2))) __fp16;   // cvt_pkrtz return type
using f32x16 = __attribute__((ext_vector_type(16))) float;
using uint2v = __attribute__((ext_vector_type(2))) unsigned;
using uint4v = __attribute__((ext_vector_type(4))) unsigned;

struct C { float r, i; };

__device__ __forceinline__ C cmul(C a, C b) {
    C o;
    o.r = fmaf(a.r, b.r, -(a.i * b.i));
    o.i = fmaf(a.r, b.i,   a.i * b.r);
    return o;
}

// o = u*a + w*b where u=(ur,ui), w=(wr,wi) are gate entries.
__device__ __forceinline__ C cmadd(float ur, float ui, float wr, float wi, C a, C b) {
    C o;
    o.r = fmaf(ur, a.r, fmaf(-ui, a.i, fmaf(wr, b.r, -(wi * b.i))));
    o.i = fmaf(ur, a.i, fmaf( ui, a.r, fmaf(wr, b.i,   wi * b.r)));
    return o;
}

template <int BP>
__device__ __forceinline__ void apply_gate(C st[16], float4 A4, float4 B4) {
#pragma unroll
    for (int i = 0; i < 8; i++) {
        const int lo = ((i >> BP) << (BP + 1)) | (i & ((1 << BP) - 1));
        const int hi = lo | (1 << BP);
        const C a = st[lo], b = st[hi];
        st[lo] = cmadd(A4.x, A4.y, A4.z, A4.w, a, b);
        st[hi] = cmadd(B4.x, B4.y, B4.z, B4.w, a, b);
    }
}

template <int CB, int TB>
__device__ __forceinline__ void cnot(C st[16]) {
#pragma unroll
    for (int i = 0; i < 16; i++) {
        if ((i & (1 << CB)) && !(i & (1 << TB))) {
            C t = st[i];
            st[i] = st[i | (1 << TB)];
            st[i | (1 << TB)] = t;
        }
    }
}

struct Enc { float r0, i0, r1, i1; };
// v_q = (cos(xn) e^{-i xn/2}, sin(xn) e^{+i xn/2}), xn = pi*tanh(x).
// HW v_sin/v_cos take REVOLUTIONS: sin(pi t/2) = v_sin(t/4), t in (-1,1).
__device__ __forceinline__ Enc encode(float xq) {
    const float ax = fabsf(xq);
    const float e  = __builtin_amdgcn_exp2f(ax * -2.8853900817779268f);  // exp(-2|x|)
    const float r  = __builtin_amdgcn_rcpf(1.0f + e);
    const float t  = copysignf((1.0f - e) * r, xq);                       // tanh(x)
    const float sh = __builtin_amdgcn_sinf(t * 0.25f);                    // sin(pi t/2)
    const float ch = __builtin_amdgcn_cosf(t * 0.25f);                    // cos(pi t/2)
    const float s  = 2.0f * sh * ch;                                      // sin(pi t)
    const float c  = fmaf(-2.0f * sh, sh, 1.0f);                          // cos(pi t)
    return {c * ch, -(c * sh), s * ch, s * sh};
}

// ---------------- Kernel 1: compose W_full (1 block, 64 threads) -------------
// W_full = Ring L2 Ring L1 Ring (L0 Rot): includes the sample-independent
// layer-0 Rot gates (folded), stored hi-only f16 [32][32] at ws[0,2048).
__global__ void qcompose_kernel(const float* __restrict__ qw, float* __restrict__ ws) {
    __shared__ float4 Ug[12][2];
    const int tid = threadIdx.x;
    if (tid < 12) {
        const float phi = qw[tid * 3 + 0];
        const float th  = qw[tid * 3 + 1];
        const float om  = qw[tid * 3 + 2];
        // Rot = RZ(om) RY(th) RZ(phi)
        float s, c;   __sincosf(0.5f * th, &s, &c);
        float sa, ca; __sincosf(0.5f * (phi + om), &sa, &ca);
        float sb, cb; __sincosf(0.5f * (phi - om), &sb, &cb);
        Ug[tid][0] = make_float4(c * ca, -c * sa, -s * cb, -s * sb);
        Ug[tid][1] = make_float4(s * cb, -s * sb, c * ca, c * sa);
    }
    __syncthreads();

    if (tid < 16) {
        // Push basis e_tid through: L0 Rot, ring0, L1, ring, L2, ring.
        C st[16];
#pragma unroll
        for (int i = 0; i < 16; i++) { st[i].r = 0.0f; st[i].i = 0.0f; }
        st[tid].r = 1.0f;

        apply_gate<3>(st, Ug[0][0], Ug[0][1]);   // layer-0 Rot, qubit q -> bit 3-q
        apply_gate<2>(st, Ug[1][0], Ug[1][1]);
        apply_gate<1>(st, Ug[2][0], Ug[2][1]);
        apply_gate<0>(st, Ug[3][0], Ug[3][1]);
        cnot<3, 2>(st); cnot<2, 1>(st); cnot<1, 0>(st); cnot<0, 3>(st);
        apply_gate<3>(st, Ug[4][0], Ug[4][1]);
        apply_gate<2>(st, Ug[5][0], Ug[5][1]);
        apply_gate<1>(st, Ug[6][0], Ug[6][1]);
        apply_gate<0>(st, Ug[7][0], Ug[7][1]);
        cnot<3, 2>(st); cnot<2, 1>(st); cnot<1, 0>(st); cnot<0, 3>(st);
        apply_gate<3>(st, Ug[8][0], Ug[8][1]);
        apply_gate<2>(st, Ug[9][0], Ug[9][1]);
        apply_gate<1>(st, Ug[10][0], Ug[10][1]);
        apply_gate<0>(st, Ug[11][0], Ug[11][1]);
        cnot<3, 2>(st); cnot<2, 1>(st); cnot<1, 0>(st); cnot<0, 3>(st);

        // W real rep: out[j] = sum_k W[j][k] in[k], j/k = 2*dim + (0:re,1:im).
        // Basis t -> columns (2t, 2t+1): row 2d: (Tr, -Ti)  row 2d+1: (Ti, Tr)
        _Float16* whi = reinterpret_cast<_Float16*>(ws);
        const int k0 = 2 * tid, k1 = k0 + 1;
#pragma unroll
        for (int d = 0; d < 16; d++) {
            const int j0 = 2 * d, j1 = j0 + 1;
            const float vr = st[d].r, vi = st[d].i;
            whi[j0 * 32 + k0] = (_Float16)vr;
            whi[j1 * 32 + k0] = (_Float16)vi;
            whi[j0 * 32 + k1] = (_Float16)(-vi);
            whi[j1 * 32 + k1] = (_Float16)vr;
        }
    }
}

// ---------------- Kernel 2: main, LDS-free, permlane B-assembly --------------
__global__ __launch_bounds__(256, 8) void qlayer_kernel(const float* __restrict__ x,
                                                        const float* __restrict__ ws,
                                                        float* __restrict__ out, int B) {
    const int tid  = threadIdx.x;
    const int lane = tid & 63;

    const char* wsb = reinterpret_cast<const char*>(ws);

    // W fragments = MFMA A-operand (32x32): lane holds row j=lane&31,
    // k-chunk 8*(lane>>5) of each 16-k step (round-7/9/10-verified addressing).
    const int j32 = lane & 31;
    const int h   = lane >> 5;
    const f16x8 Wh0 = *reinterpret_cast<const f16x8*>(wsb + j32 * 64 + h * 16);
    const f16x8 Wh1 = *reinterpret_cast<const f16x8*>(wsb + j32 * 64 + 32 + h * 16);

    const int b  = blockIdx.x * 256 + tid;
    const int bl = (b < B) ? b : (B - 1);   // clamp: OOB lanes still join MFMA/permlane
    const float4 xv = reinterpret_cast<const float4*>(x)[bl];
    const float xs[4] = {xv.x, xv.y, xv.z, xv.w};

    // Front end: encode only (layer-0 Rot lives inside W now).
    C v[4][2];
#pragma unroll
    for (int q = 0; q < 4; q++) {
        const Enc e = encode(xs[q]);
        v[q][0] = C{e.r0, e.i0};
        v[q][1] = C{e.r1, e.i1};
    }

    // Outer product + f16 pack: d[i] = pack(st[i].r, st[i].i), one dword/amp.
    C t01[4], t23[4];
#pragma unroll
    for (int i = 0; i < 4; i++) {
        t01[i] = cmul(v[0][(i >> 1) & 1], v[1][i & 1]);
        t23[i] = cmul(v[2][(i >> 1) & 1], v[3][i & 1]);
    }
    unsigned d[16];
#pragma unroll
    for (int i = 0; i < 16; i++) {
        const C s = cmul(t01[i >> 2], t23[i & 3]);
        const hf2 pk = __builtin_amdgcn_cvt_pkrtz(s.r, s.i);
        d[i] = __builtin_bit_cast(unsigned, pk);
    }

    // B-fragment assembly via permlane32_swap (no LDS, no fence).
    // Need: lane l<32 -> d[8s..8s+3] of lane 32n+l; lane l>=32 -> d[8s+4..8s+7]
    // of lane 32n+l-32. swap(A=d[8s+k'], B=d[8s+4+k']) semantics
    // (row1-of-A <-> row0-of-B) give newA = tile0 frag, newB = tile1 frag.
    unsigned f0a[4], f0b[4], f1a[4], f1b[4];   // tile0 {S0,S1}; tile1 {S0,S1}
#pragma unroll
    for (int k = 0; k < 4; k++) {
        const uint2v rA = __builtin_amdgcn_permlane32_swap(d[k],     d[4 + k],  false, false);
        f0a[k] = rA.x;  f1a[k] = rA.y;
        const uint2v rB = __builtin_amdgcn_permlane32_swap(d[8 + k], d[12 + k], false, false);
        f0b[k] = rB.x;  f1b[k] = rB.y;
    }
    f16x8 S0v[2], S1v[2];
    {
        const uint4v a0 = {f0a[0], f0a[1], f0a[2], f0a[3]};
        const uint4v b0 = {f0b[0], f0b[1], f0b[2], f0b[3]};
        const uint4v a1 = {f1a[0], f1a[1], f1a[2], f1a[3]};
        const uint4v b1 = {f1b[0], f1b[1], f1b[2], f1b[3]};
        S0v[0] = __builtin_bit_cast(f16x8, a0);
        S1v[0] = __builtin_bit_cast(f16x8, b0);
        S0v[1] = __builtin_bit_cast(f16x8, a1);
        S1v[1] = __builtin_bit_cast(f16x8, b1);
    }

    // Tail: D = W * S^T, 32x32x16, 2 chained k-steps, 2 sample-tiles of 32.
    // D layout (verified r7/r9/r10): col = sample = lane&31,
    // row = (reg&3)+8*(reg>>2)+4h; pairs (2m,2m+1) = (re,im) of
    // d(m) = 4*(m>>1) + 2h + (m&1). Own tile = h.
    float r3[2], r2[2], r1[2], r0[2];
#pragma unroll
    for (int n = 0; n < 2; n++) {
        const f32x16 Z = {0.f,0.f,0.f,0.f,0.f,0.f,0.f,0.f,
                          0.f,0.f,0.f,0.f,0.f,0.f,0.f,0.f};
        f32x16 D = __builtin_amdgcn_mfma_f32_32x32x16_f16(Wh0, S0v[n], Z, 0, 0, 0);
        D        = __builtin_amdgcn_mfma_f32_32x32x16_f16(Wh1, S1v[n], D, 0, 0, 0);

        float p[8];
#pragma unroll
        for (int m = 0; m < 8; m++)
            p[m] = fmaf(D[2 * m + 1], D[2 * m + 1], D[2 * m] * D[2 * m]);

        const float e67 = p[6] + p[7];
        float t3 = (p[4] + p[5]) + e67;                    // d&8: m=4..7
        float t2 = (p[2] + p[3]) + e67;                    // d&4: m=2,3,6,7
        float t0 = (p[1] + p[3]) + (p[5] + p[7]);          // d&1: m odd
        const float tAll = ((p[0] + p[2]) + (p[4] + p[6])) + t0;
        float t1 = h ? tAll : 0.0f;                        // d&2 <=> h
        t3 += __shfl_xor(t3, 32); t2 += __shfl_xor(t2, 32);
        t1 += __shfl_xor(t1, 32); t0 += __shfl_xor(t0, 32);
        r3[n] = t3; r2[n] = t2; r1[n] = t1; r0[n] = t0;
    }
    const float e3 = h ? r3[1] : r3[0];
    const float e2 = h ? r2[1] : r2[0];
    const float e1 = h ? r1[1] : r1[0];
    const float e0 = h ? r0[1] : r0[0];

    if (b < B) {
        float4 ev;
        ev.x = fmaf(-2.0f, e3, 1.0f);
        ev.y = fmaf(-2.0f, e2, 1.0f);
        ev.z = fmaf(-2.0f, e1, 1.0f);
        ev.w = fmaf(-2.0f, e0, 1.0f);
        reinterpret_cast<float4*>(out)[b] = ev;
    }
}

extern "C" void kernel_launch(void* const* d_in, const int* in_sizes, int n_in,
                              void* d_out, int out_size, void* d_ws, size_t ws_size,
                              hipStream_t stream) {
    const float* x  = (const float*)d_in[0];
    const float* qw = (const float*)d_in[1];
    float* out = (float*)d_out;
    float* ws  = (float*)d_ws;
    const int B = in_sizes[0] / 4;
    const int blocks = (B + 255) / 256;   // one 256-sample chunk per block
    qcompose_kernel<<<1, 64, 0, stream>>>(qw, ws);
    qlayer_kernel<<<blocks, 256, 0, stream>>>(x, ws, out, B);
}